// Round 2
// baseline (1141.984 us; speedup 1.0000x reference)
//
#include <hip/hip_runtime.h>

// SAERTextRNN on MI355X (gfx950).
// Dims: S=32, B=32, V=32000, H=512, DIN=512, F=50, NL=2.
// Float tensors may arrive as bf16 OR fp32 (harness-dependent); k_detect decides
// at runtime, k_convert canonicalizes small tensors to bf16, big tensors
// (word_ebd, Wout) and d_out get dual-mode access.
// Large scratch lives in d_out (fully rewritten by k_big later); ws holds only
// what must survive k_big (~1.6 MB).

typedef unsigned short u16;
typedef short s16x8 __attribute__((ext_vector_type(8)));
typedef float f32x4 __attribute__((ext_vector_type(4)));

__device__ __forceinline__ float b2f(u16 u) {
    unsigned int x = ((unsigned int)u) << 16; float f; __builtin_memcpy(&f, &x, 4); return f;
}
__device__ __forceinline__ u16 f2b(float f) {
    unsigned int u; __builtin_memcpy(&u, &f, 4);
    unsigned int r = (u + 0x7fffu + ((u >> 16) & 1u)) >> 16; return (u16)r;
}
__device__ __forceinline__ float sigf(float x) { return 1.0f / (1.0f + expf(-x)); }
__device__ __forceinline__ f32x4 mfma(s16x8 a, s16x8 b, f32x4 c) {
    return __builtin_amdgcn_mfma_f32_16x16x32_bf16(a, b, c, 0, 0, 0);
}
// dual-mode 8-element fragment load (elem_off in elements)
__device__ __forceinline__ s16x8 ld8_dual(const void* base, size_t elem_off, bool isf) {
    s16x8 r;
    if (!isf) {
        r = *(const s16x8*)((const u16*)base + elem_off);
    } else {
        const float* f = (const float*)base + elem_off;
        float4 a = *(const float4*)f, b = *(const float4*)(f + 4);
        r[0] = (short)f2b(a.x); r[1] = (short)f2b(a.y); r[2] = (short)f2b(a.z); r[3] = (short)f2b(a.w);
        r[4] = (short)f2b(b.x); r[5] = (short)f2b(b.y); r[6] = (short)f2b(b.z); r[7] = (short)f2b(b.w);
    }
    return r;
}
__device__ __forceinline__ float ld_out1(const void* o, size_t i, bool isf) {
    return isf ? ((const float*)o)[i] : b2f(((const u16*)o)[i]);
}
__device__ __forceinline__ void st_out1(void* o, size_t i, float v, bool isf) {
    if (isf) ((float*)o)[i] = v; else ((u16*)o)[i] = f2b(v);
}

// ---- inter-WG step sync (bounded spin: bug -> wrong answer, not hang) ----
__device__ __forceinline__ void gwait(int* p, int target) {
    if (threadIdx.x == 0) {
        int it = 0;
        while (__hip_atomic_load(p, __ATOMIC_ACQUIRE, __HIP_MEMORY_SCOPE_AGENT) < target) {
            __builtin_amdgcn_s_sleep(4);
            if (++it > (1 << 21)) break;
        }
    }
    __syncthreads();
}
__device__ __forceinline__ void gpost(int* p) {
    __threadfence();
    __syncthreads();
    if (threadIdx.x == 0) __hip_atomic_fetch_add(p, 1, __ATOMIC_RELEASE, __HIP_MEMORY_SCOPE_AGENT);
}

// ---- dtype detect: even-index u16s of word_ebd. bf16 -> exponent concentrated ----
__global__ __launch_bounds__(256) void k_detect(const u16* __restrict__ we, int* flagp) {
    __shared__ int cnt[256];
    int tid = threadIdx.x, c = 0;
    for (int i = 0; i < 16; ++i) {
        u16 u = we[(tid * 16 + i) * 2];
        int e = (u >> 7) & 0xFF;
        c += (e >= 0x68 && e <= 0x7F) ? 1 : 0;
    }
    cnt[tid] = c; __syncthreads();
    for (int s = 128; s > 0; s >>= 1) { if (tid < s) cnt[tid] += cnt[tid + s]; __syncthreads(); }
    if (tid == 0) *flagp = (cnt[0] < 2048) ? 1 : 0;  // 1 = fp32, 0 = bf16
}

// ---- canonicalize 24 small/medium tensors to bf16 ----
struct CArgs { const void* src[24]; int off[25]; int real[24]; };
__global__ __launch_bounds__(256) void k_convert(CArgs a, u16* __restrict__ canon, const int* flagp) {
    int t = blockIdx.x * 256 + threadIdx.x;
    if (t >= a.off[24]) return;
    int i = 0;
#pragma unroll
    for (int j = 1; j < 24; ++j) i += (t >= a.off[j]) ? 1 : 0;
    int local = t - a.off[i];
    u16 v = 0;
    if (local < a.real[i]) {
        if (*flagp) v = f2b(((const float*)a.src[i])[local]);
        else v = ((const u16*)a.src[i])[local];
    }
    canon[t] = v;
}

// ---- pack GRU weights into MFMA-fragment order (inputs: canonical bf16) ----
__global__ __launch_bounds__(256) void k_pack(const u16* __restrict__ Whh0,
                                              const u16* __restrict__ Wih1,
                                              const u16* __restrict__ Whh1,
                                              u16* __restrict__ p0, u16* __restrict__ p1) {
    int cid = blockIdx.x * 256 + threadIdx.x;
    if (cid < 98304) {
        int lane = cid & 63, rest = cid >> 6;
        int k0 = rest & 15, st = rest >> 4;
        int tile = st % 3, s = st / 3;
        int r16 = lane & 15, q = lane >> 4;
        int srow = tile * 512 + s * 16 + r16;
        *(s16x8*)(p0 + (size_t)cid * 8) = *(const s16x8*)(Whh0 + (size_t)srow * 512 + k0 * 32 + q * 8);
    } else if (cid < 98304 + 262144) {
        int c2 = cid - 98304;
        int lane = c2 & 63, rest = c2 >> 6;
        int k0 = rest & 15, st = rest >> 4;
        int tile = st & 3, s = st >> 2;
        int r16 = lane & 15, q = lane >> 4;
        int mat = tile >> 1, tt = tile & 1, u0 = s * 8;
        s16x8 v;
        bool pad = (tt == 1) && (r16 >= 8);
        if (pad) {
            for (int e = 0; e < 8; ++e) v[e] = 0;
        } else {
            int srow = (tt == 0) ? ((r16 < 8) ? (u0 + r16) : (512 + u0 + r16 - 8))
                                 : (1024 + u0 + r16);
            const u16* W = mat ? Whh1 : Wih1;
            v = *(const s16x8*)(W + (size_t)srow * 512 + k0 * 32 + q * 8);
        }
        *(s16x8*)(p1 + (size_t)c2 * 8) = v;
    }
}

// ---- wave-per-16x16-tile GEMM: C[m,n] = sum_k A[m,k]*B[n,k] + bias ----
// A dual-mode (amode=1: dtype per flag), optional row gather. B/bias canonical bf16.
// mode 0: outF fp32.  mode 1: outH bf16 = tanh(acc + bias + rg[m]*so[(m&31)*512+n])
__global__ __launch_bounds__(256) void k_gemm(const void* __restrict__ A, int amode,
                                              const int* __restrict__ gidx,
                                              const u16* __restrict__ B, const u16* __restrict__ bias,
                                              float* outF, u16* outH, int M, int N, int K, int mode,
                                              const float* __restrict__ rgv, const float* __restrict__ so,
                                              const int* __restrict__ flagp) {
    int wid = blockIdx.x * 4 + (threadIdx.x >> 6);
    int Nt = N >> 4;
    if (wid >= (M >> 4) * Nt) return;
    bool isf = amode && (*flagp != 0);
    int mt = wid / Nt, nt = wid - mt * Nt;
    int lane = threadIdx.x & 63, L15 = lane & 15, q = lane >> 4;
    int am = mt * 16 + L15;
    size_t arow = gidx ? (size_t)gidx[am] : (size_t)am;
    size_t abase = arow * (size_t)K + q * 8;
    const u16* bp = B + (size_t)(nt * 16 + L15) * K + q * 8;
    f32x4 acc = {0.f, 0.f, 0.f, 0.f};
    for (int k0 = 0; k0 < (K >> 5); ++k0) {
        s16x8 a = ld8_dual(A, abase + k0 * 32, isf);
        s16x8 b = *(const s16x8*)(bp + k0 * 32);
        acc = mfma(a, b, acc);
    }
    int n = nt * 16 + L15;
    float bb = b2f(bias[n]);
#pragma unroll
    for (int i = 0; i < 4; ++i) {
        int m = mt * 16 + q * 4 + i;
        float v = acc[i] + bb;
        if (mode == 0) {
            outF[(size_t)m * N + n] = v;
        } else {
            v += rgv[m] * so[(size_t)(m & 31) * 512 + n];
            outH[(size_t)m * N + n] = f2b(tanhf(v));
        }
    }
}

// ---- persistent GRU: blocks 0..31 layer0 (16 units), 32..95 layer1 (8 units) ----
__global__ __launch_bounds__(256) void k_gru(const u16* __restrict__ p0, const u16* __restrict__ p1,
                                             const float* __restrict__ gi0,
                                             const u16* __restrict__ bhh0, const u16* __restrict__ bih1,
                                             const u16* __restrict__ bhh1, const u16* __restrict__ inith,
                                             u16* __restrict__ y0, u16* __restrict__ y1,
                                             int* cnt0, int* cnt1) {
    __shared__ __align__(16) unsigned char smem[65536];
    u16* B1 = (u16*)smem;
    u16* B2 = (u16*)(smem + 32768);
    int tid = threadIdx.x;
    int lane = tid & 63, wave = tid >> 6, L15 = lane & 15, q = lane >> 4;
    int bx = blockIdx.x;

    if (bx < 32) {  // layer 0
        int u0 = bx * 16;
        float* scr = (float*)B2;
        for (int t = 0; t < 32; ++t) {
            if (t > 0) gwait(cnt0 + (t - 1), 32);
            const u16* src = (t == 0) ? inith : (y0 + (size_t)(t - 1) * 16384);
            for (int cl = tid; cl < 2048; cl += 256) {
                int n = cl >> 6, c = cl & 63;
                *(s16x8*)(B1 + n * 512 + ((c ^ (n & 7)) << 3)) = *(const s16x8*)(src + n * 512 + (c << 3));
            }
            __syncthreads();
            for (int task = wave; task < 6; task += 4) {
                int tile = task >> 1, bt = task & 1;
                const u16* ap = p0 + (size_t)((bx * 3 + tile) * 16) * 512 + lane * 8;
                f32x4 acc = {0.f, 0.f, 0.f, 0.f};
                int n = bt * 16 + L15;
#pragma unroll
                for (int k0 = 0; k0 < 16; ++k0) {
                    s16x8 a = *(const s16x8*)(ap + k0 * 512);
                    s16x8 b = *(const s16x8*)(B1 + n * 512 + ((((k0 << 2) + q) ^ (n & 7)) << 3));
                    acc = mfma(a, b, acc);
                }
#pragma unroll
                for (int i = 0; i < 4; ++i) scr[(tile * 16 + q * 4 + i) * 32 + n] = acc[i];
            }
            __syncthreads();
            for (int it = 0; it < 2; ++it) {
                int slot = it * 256 + tid;
                int u = slot & 15, b = slot >> 4;
                int gu = u0 + u;
                const float* gm = gi0 + ((size_t)t * 32 + b) * 1536;
                float ir = gm[gu], iz = gm[512 + gu], inn = gm[1024 + gu];
                float hr = scr[u * 32 + b] + b2f(bhh0[gu]);
                float hz = scr[(16 + u) * 32 + b] + b2f(bhh0[512 + gu]);
                float hn = scr[(32 + u) * 32 + b] + b2f(bhh0[1024 + gu]);
                float r = sigf(ir + hr), z = sigf(iz + hz);
                float nn = tanhf(inn + r * hn);
                float hp = b2f(B1[b * 512 + (((gu >> 3) ^ (b & 7)) << 3) + (gu & 7)]);
                float h2 = (1.0f - z) * nn + z * hp;
                y0[((size_t)t * 32 + b) * 512 + gu] = f2b(h2);
            }
            gpost(cnt0 + t);
        }
    } else {  // layer 1
        int wg = bx - 32, u0 = wg * 8;
        for (int t = 0; t < 32; ++t) {
            gwait(cnt0 + t, 32);
            if (t > 0) gwait(cnt1 + (t - 1), 64);
            const u16* srcA = y0 + (size_t)t * 16384;
            const u16* srcB = (t == 0) ? (inith + 16384) : (y1 + (size_t)(t - 1) * 16384);
            for (int cl = tid; cl < 2048; cl += 256) {
                int n = cl >> 6, c = cl & 63;
                *(s16x8*)(B1 + n * 512 + ((c ^ (n & 7)) << 3)) = *(const s16x8*)(srcA + n * 512 + (c << 3));
                *(s16x8*)(B2 + n * 512 + ((c ^ (n & 7)) << 3)) = *(const s16x8*)(srcB + n * 512 + (c << 3));
            }
            __syncthreads();
            int tile = wave, mat = tile >> 1;
            const u16* bsrc = mat ? B2 : B1;
            const u16* ap = p1 + (size_t)((wg * 4 + tile) * 16) * 512 + lane * 8;
            f32x4 acc0 = {0.f, 0.f, 0.f, 0.f}, acc1 = {0.f, 0.f, 0.f, 0.f};
            int n0 = L15, n1 = 16 + L15;
#pragma unroll
            for (int k0 = 0; k0 < 16; ++k0) {
                s16x8 a = *(const s16x8*)(ap + k0 * 512);
                s16x8 b0 = *(const s16x8*)(bsrc + n0 * 512 + ((((k0 << 2) + q) ^ (n0 & 7)) << 3));
                s16x8 b1 = *(const s16x8*)(bsrc + n1 * 512 + ((((k0 << 2) + q) ^ (n1 & 7)) << 3));
                acc0 = mfma(a, b0, acc0);
                acc1 = mfma(a, b1, acc1);
            }
            __syncthreads();
            float* scr = (float*)B1;
            int rl = (tile & 1) * 16 + q * 4;
#pragma unroll
            for (int i = 0; i < 4; ++i) {
                scr[(mat * 32 + rl + i) * 32 + n0] = acc0[i];
                scr[(mat * 32 + rl + i) * 32 + n1] = acc1[i];
            }
            __syncthreads();
            {
                int u = tid & 7, b = tid >> 3;
                int gu = u0 + u;
                float ir = scr[u * 32 + b] + b2f(bih1[gu]);
                float iz = scr[(8 + u) * 32 + b] + b2f(bih1[512 + gu]);
                float inn = scr[(16 + u) * 32 + b] + b2f(bih1[1024 + gu]);
                float hr = scr[(32 + u) * 32 + b] + b2f(bhh1[gu]);
                float hz = scr[(40 + u) * 32 + b] + b2f(bhh1[512 + gu]);
                float hn = scr[(48 + u) * 32 + b] + b2f(bhh1[1024 + gu]);
                float r = sigf(ir + hr), z = sigf(iz + hz);
                float nn = tanhf(inn + r * hn);
                float hp = b2f(B2[b * 512 + (((gu >> 3) ^ (b & 7)) << 3) + (gu & 7)]);
                float h2 = (1.0f - z) * nn + z * hp;
                y1[((size_t)t * 32 + b) * 512 + gu] = f2b(h2);
            }
            gpost(cnt1 + t);
        }
    }
}

// ---- fs(16), fg, rg per (s,b) row ----
__global__ __launch_bounds__(64) void k_fsfgrg(const u16* __restrict__ y1,
                                               const u16* __restrict__ Wfs, const u16* __restrict__ bfs,
                                               const u16* __restrict__ Wfg, const u16* __restrict__ bfg,
                                               const u16* __restrict__ Wrg, const u16* __restrict__ brg,
                                               float* fsv, float* fgv, float* rgv) {
    int m = blockIdx.x, lane = threadIdx.x;
    s16x8 av = *(const s16x8*)(y1 + (size_t)m * 512 + lane * 8);
    float af[8];
#pragma unroll
    for (int e = 0; e < 8; ++e) af[e] = b2f((u16)av[e]);
    for (int j = 0; j < 18; ++j) {
        const u16* w = (j < 16) ? (Wfs + (size_t)j * 512) : ((j == 16) ? Wfg : Wrg);
        s16x8 wv = *(const s16x8*)(w + lane * 8);
        float p = 0.f;
#pragma unroll
        for (int e = 0; e < 8; ++e) p += af[e] * b2f((u16)wv[e]);
        for (int off = 32; off > 0; off >>= 1) p += __shfl_xor(p, off);
        if (lane == 0) {
            if (j < 16) fsv[(size_t)m * 16 + j] = p + b2f(bfs[j]);
            else if (j == 16) fgv[m] = sigf(p + b2f(bfg[0]));
            else rgv[m] = sigf(p + b2f(brg[0]));
        }
    }
}

// ---- attention softmax over F=50 (if_mask all-true) ----
__global__ __launch_bounds__(64) void k_attn(const float* __restrict__ fsv,
                                             const u16* __restrict__ user, const u16* __restrict__ item,
                                             const float* __restrict__ energy, float* __restrict__ fattn) {
    int m = blockIdx.x, b = m & 31, f = threadIdx.x;
    __shared__ float qv[80];
    for (int j = f; j < 80; j += 64)
        qv[j] = (j < 16) ? fsv[(size_t)m * 16 + j]
                         : ((j < 48) ? b2f(user[b * 32 + (j - 16)]) : b2f(item[b * 32 + (j - 48)]));
    __syncthreads();
    float sc = -1e30f;
    if (f < 50) {
        const float* ep = energy + ((size_t)b * 50 + f) * 80;
        float s = 0.f;
        for (int e = 0; e < 80; ++e) s += qv[e] * ep[e];
        sc = s;
    }
    float mx = sc;
    for (int off = 32; off > 0; off >>= 1) mx = fmaxf(mx, __shfl_xor(mx, off));
    float ev = (f < 50) ? expf(sc - mx) : 0.f;
    float sm = ev;
    for (int off = 32; off > 0; off >>= 1) sm += __shfl_xor(sm, off);
    if (f < 50) fattn[(size_t)m * 50 + f] = ev / sm;
}

// ---- score_out = ui_var @ Wso^T + bso ----
__global__ __launch_bounds__(256) void k_scoreout(const u16* __restrict__ ui, const u16* __restrict__ Wso,
                                                  const u16* __restrict__ bso, float* so) {
    int b = blockIdx.x, tid = threadIdx.x;
    __shared__ float uiL[32];
    if (tid < 32) uiL[tid] = b2f(ui[b * 32 + tid]);
    __syncthreads();
    for (int n = tid; n < 512; n += 256) {
        float s = b2f(bso[n]);
        const u16* w = Wso + (size_t)n * 32;
        for (int k = 0; k < 32; ++k) s += uiL[k] * b2f(w[k]);
        so[(size_t)b * 512 + n] = s;
    }
}

// ---- big GEMM: out = ho @ Wout^T + bout (dual-mode Wout/bout/out) ----
__global__ __launch_bounds__(256) void k_big(const u16* __restrict__ A, const void* __restrict__ W,
                                             const void* __restrict__ boutp, void* __restrict__ out,
                                             const int* __restrict__ flagp) {
    __shared__ __align__(16) u16 lA[8192], lB[8192];
    bool isf = (*flagp != 0);
    int tid = threadIdx.x;
    int bm = blockIdx.x & 15, bn = blockIdx.x >> 4;
    int lane = tid & 63, wave = tid >> 6, L15 = lane & 15, q = lane >> 4;
    f32x4 zero = {0.f, 0.f, 0.f, 0.f};
    f32x4 acc[4] = {zero, zero, zero, zero};
    int cs = tid & 15, rs = tid >> 4;
    for (int ko = 0; ko < 4; ++ko) {
        __syncthreads();
        for (int rr = rs; rr < 64; rr += 16) {
            *(s16x8*)(lA + ((rr * 16 + (cs ^ (rr & 7))) << 3)) =
                *(const s16x8*)(A + (size_t)(bm * 64 + rr) * 512 + ko * 128 + cs * 8);
            *(s16x8*)(lB + ((rr * 16 + (cs ^ (rr & 7))) << 3)) =
                ld8_dual(W, (size_t)(bn * 64 + rr) * 512 + ko * 128 + cs * 8, isf);
        }
        __syncthreads();
        int ra = wave * 16 + L15;
#pragma unroll
        for (int k0 = 0; k0 < 4; ++k0) {
            int cc = k0 * 4 + q;
            s16x8 a = *(const s16x8*)(lA + ((ra * 16 + (cc ^ (ra & 7))) << 3));
#pragma unroll
            for (int ct = 0; ct < 4; ++ct) {
                int rb = ct * 16 + L15;
                s16x8 b = *(const s16x8*)(lB + ((rb * 16 + (cc ^ (rb & 7))) << 3));
                acc[ct] = mfma(a, b, acc[ct]);
            }
        }
    }
#pragma unroll
    for (int ct = 0; ct < 4; ++ct) {
        int n = bn * 64 + ct * 16 + L15;
        float bb = isf ? ((const float*)boutp)[n] : b2f(((const u16*)boutp)[n]);
#pragma unroll
        for (int i = 0; i < 4; ++i) {
            int m = bm * 64 + wave * 16 + q * 4 + i;
            st_out1(out, (size_t)m * 32000 + n, acc[ct][i] + bb, isf);
        }
    }
}

// ---- per-row max & exp-sum; D = log(1-fg) - log Z - m ----
__global__ __launch_bounds__(256) void k_rowsum(const void* __restrict__ out, const float* __restrict__ fgv,
                                                float* Dv, float* Zv, float* Mv, const int* __restrict__ flagp) {
    bool isf = (*flagp != 0);
    int row = blockIdx.x, tid = threadIdx.x;
    __shared__ float red[256];
    float mx = -1e30f;
    for (int c = tid; c < 4000; c += 256) {
        float v[8];
        if (isf) {
            const float* p = (const float*)out + (size_t)row * 32000 + c * 8;
            float4 x = *(const float4*)p, y = *(const float4*)(p + 4);
            v[0]=x.x; v[1]=x.y; v[2]=x.z; v[3]=x.w; v[4]=y.x; v[5]=y.y; v[6]=y.z; v[7]=y.w;
        } else {
            s16x8 h = *(const s16x8*)((const u16*)out + (size_t)row * 32000 + c * 8);
#pragma unroll
            for (int e = 0; e < 8; ++e) v[e] = b2f((u16)h[e]);
        }
#pragma unroll
        for (int e = 0; e < 8; ++e) mx = fmaxf(mx, v[e]);
    }
    red[tid] = mx; __syncthreads();
    for (int s = 128; s > 0; s >>= 1) { if (tid < s) red[tid] = fmaxf(red[tid], red[tid + s]); __syncthreads(); }
    mx = red[0]; __syncthreads();
    float sum = 0.f;
    for (int c = tid; c < 4000; c += 256) {
        float v[8];
        if (isf) {
            const float* p = (const float*)out + (size_t)row * 32000 + c * 8;
            float4 x = *(const float4*)p, y = *(const float4*)(p + 4);
            v[0]=x.x; v[1]=x.y; v[2]=x.z; v[3]=x.w; v[4]=y.x; v[5]=y.y; v[6]=y.z; v[7]=y.w;
        } else {
            s16x8 h = *(const s16x8*)((const u16*)out + (size_t)row * 32000 + c * 8);
#pragma unroll
            for (int e = 0; e < 8; ++e) v[e] = b2f((u16)h[e]);
        }
#pragma unroll
        for (int e = 0; e < 8; ++e) sum += expf(v[e] - mx);
    }
    red[tid] = sum; __syncthreads();
    for (int s = 128; s > 0; s >>= 1) { if (tid < s) red[tid] += red[tid + s]; __syncthreads(); }
    if (tid == 0) {
        float Z = red[0], fg = fgv[row];
        Mv[row] = mx; Zv[row] = Z;
        Dv[row] = logf(1.0f - fg) - logf(Z) - mx;
    }
}

// ---- save raw logits at scattered indices ----
__global__ __launch_bounds__(256) void k_grab(const void* __restrict__ out, const int* __restrict__ ifeat,
                                              float* __restrict__ tmpl, const int* __restrict__ flagp) {
    bool isf = (*flagp != 0);
    int id = blockIdx.x * 256 + threadIdx.x;
    if (id >= 51200) return;
    int m = id / 50, f = id - m * 50, b = m & 31;
    int idx = ifeat[b * 50 + f];
    tmpl[id] = ld_out1(out, (size_t)m * 32000 + idx, isf);
}

// ---- in-place: out = l + D[row] ----
__global__ __launch_bounds__(256) void k_final(void* __restrict__ out, const float* __restrict__ Dv,
                                               const int* __restrict__ flagp) {
    bool isf = (*flagp != 0);
    int row = blockIdx.y;
    int c = blockIdx.x * 256 + threadIdx.x;
    if (c >= 4000) return;
    float D = Dv[row];
    size_t base = (size_t)row * 32000 + (size_t)c * 8;
    if (isf) {
        float* p = (float*)out + base;
        float4 x = *(const float4*)p, y = *(const float4*)(p + 4);
        x.x += D; x.y += D; x.z += D; x.w += D;
        y.x += D; y.y += D; y.z += D; y.w += D;
        *(float4*)p = x; *(float4*)(p + 4) = y;
    } else {
        u16* p = (u16*)out + base;
        s16x8 v = *(const s16x8*)p, r;
#pragma unroll
        for (int e = 0; e < 8; ++e) r[e] = (short)f2b(b2f((u16)v[e]) + D);
        *(s16x8*)p = r;
    }
}

// ---- exact fix-up at scattered entries ----
__global__ __launch_bounds__(256) void k_fixup(const float* __restrict__ tmpl, const int* __restrict__ ifeat,
                                               const float* __restrict__ Mv, const float* __restrict__ Zv,
                                               const float* __restrict__ fgv, const float* __restrict__ fattn,
                                               void* __restrict__ out, const int* __restrict__ flagp) {
    bool isf = (*flagp != 0);
    int id = blockIdx.x * 256 + threadIdx.x;
    if (id >= 51200) return;
    int m = id / 50, f = id - m * 50, b = m & 31;
    int idx = ifeat[b * 50 + f];
    float p = expf(tmpl[id] - Mv[m]) / Zv[m];
    float fg = fgv[m];
    float val = (1.0f - fg) * p + fg * fattn[(size_t)m * 50 + f];
    st_out1(out, (size_t)m * 32000 + idx, logf(val), isf);
}

extern "C" void kernel_launch(void* const* d_in, const int* in_sizes, int n_in,
                              void* d_out, int out_size, void* d_ws, size_t ws_size,
                              hipStream_t stream) {
    const int* input_seq = (const int*)d_in[0];
    const int* i_features = (const int*)d_in[5];
    const void* word_ebd = d_in[7];
    const void* Wout = d_in[16];
    const void* bout = d_in[17];
    char* ob = (char*)d_out;
    char* w = (char*)d_ws;

    // ws layout (~1.61 MB): only things alive during/after k_big
    int* cnt0 = (int*)(w + 0);
    int* cnt1 = (int*)(w + 128);
    int* flagp = (int*)(w + 256);
    float* Dv = (float*)(w + 512);
    float* Zv = (float*)(w + 4608);
    float* Mv = (float*)(w + 8704);
    float* fgv = (float*)(w + 12800);
    float* rgv = (float*)(w + 16896);
    float* fsv = (float*)(w + 20992);    // 64 KB
    float* so = (float*)(w + 86528);     // 64 KB
    float* fattn = (float*)(w + 152064); // 200 KB
    float* tmpl = (float*)(w + 356864);  // 200 KB
    u16* ho = (u16*)(w + 561664);        // 1 MB -> ends 1,610,240

    // d_out scratch (all consumed before k_big rewrites d_out)
    u16* canon = (u16*)(ob + 0);             // 7,035,104 B
    u16* p0 = (u16*)(ob + 7035136);          // 1.5 MB
    u16* p1 = (u16*)(ob + 8608000);          // 4 MB
    float* gi0 = (float*)(ob + 12802304);    // 6 MB
    float* energy = (float*)(ob + 19093760); // 0.5 MB
    u16* y0 = (u16*)(ob + 19605760);         // 1 MB
    u16* y1 = (u16*)(ob + 20654336);         // 1 MB -> ends 21,702,912 (< 65.5 MB)

    // canonical tensor table
    static const int din_idx[24] = {1,2,3,4, 8,9,10,11, 12,13,14,15, 18,19,20,21, 22,23,24,25, 26,27,28,29};
    static const int padsz[24] = {32768,1024,1024,1024, 786432,786432,1536,1536, 786432,786432,1536,1536,
                                  512,8,16384,512, 262144,512,512,8, 8192,16,40960,80};
    CArgs ca;
    int off = 0;
    for (int i = 0; i < 24; ++i) {
        ca.src[i] = d_in[din_idx[i]];
        ca.off[i] = off;
        ca.real[i] = padsz[i];
        off += padsz[i];
    }
    ca.real[13] = 1; ca.real[19] = 1;  // brg, bfg are scalars
    ca.off[24] = off;                  // 3,517,552 elements
    const u16 *c_inith = canon + ca.off[0], *c_user = canon + ca.off[1], *c_item = canon + ca.off[2],
              *c_uivar = canon + ca.off[3], *c_Wih0 = canon + ca.off[4], *c_Whh0 = canon + ca.off[5],
              *c_bih0 = canon + ca.off[6], *c_bhh0 = canon + ca.off[7], *c_Wih1 = canon + ca.off[8],
              *c_Whh1 = canon + ca.off[9], *c_bih1 = canon + ca.off[10], *c_bhh1 = canon + ca.off[11],
              *c_Wrg = canon + ca.off[12], *c_brg = canon + ca.off[13], *c_Wso = canon + ca.off[14],
              *c_bso = canon + ca.off[15], *c_Woo = canon + ca.off[16], *c_boo = canon + ca.off[17],
              *c_Wfg = canon + ca.off[18], *c_bfg = canon + ca.off[19], *c_Wfs = canon + ca.off[20],
              *c_bfs = canon + ca.off[21], *c_Wfa = canon + ca.off[22], *c_bfa = canon + ca.off[23];

    hipMemsetAsync(d_ws, 0, 512, stream);  // counters + flag
    k_detect<<<1, 256, 0, stream>>>((const u16*)word_ebd, flagp);
    k_convert<<<(off + 255) / 256, 256, 0, stream>>>(ca, canon, flagp);
    k_pack<<<1408, 256, 0, stream>>>(c_Whh0, c_Wih1, c_Whh1, p0, p1);
    k_gemm<<<1536, 256, 0, stream>>>(word_ebd, 1, input_seq, c_Wih0, c_bih0, gi0, nullptr,
                                     1024, 1536, 512, 0, nullptr, nullptr, flagp);
    k_gemm<<<125, 256, 0, stream>>>(word_ebd, 1, i_features, c_Wfa, c_bfa, energy, nullptr,
                                    1600, 80, 512, 0, nullptr, nullptr, flagp);
    k_scoreout<<<32, 256, 0, stream>>>(c_uivar, c_Wso, c_bso, so);
    k_gru<<<96, 256, 0, stream>>>(p0, p1, gi0, c_bhh0, c_bih1, c_bhh1, c_inith, y0, y1, cnt0, cnt1);
    k_fsfgrg<<<1024, 64, 0, stream>>>(y1, c_Wfs, c_bfs, c_Wfg, c_bfg, c_Wrg, c_brg, fsv, fgv, rgv);
    k_attn<<<1024, 64, 0, stream>>>(fsv, c_user, c_item, energy, fattn);
    k_gemm<<<512, 256, 0, stream>>>(y1, 0, nullptr, c_Woo, c_boo, nullptr, ho,
                                    1024, 512, 512, 1, rgv, so, flagp);
    k_big<<<8000, 256, 0, stream>>>(ho, Wout, bout, d_out, flagp);
    k_rowsum<<<1024, 256, 0, stream>>>(d_out, fgv, Dv, Zv, Mv, flagp);
    k_grab<<<200, 256, 0, stream>>>(d_out, i_features, tmpl, flagp);
    k_final<<<dim3(16, 1024), 256, 0, stream>>>(d_out, Dv, flagp);
    k_fixup<<<200, 256, 0, stream>>>(tmpl, i_features, Mv, Zv, fgv, fattn, d_out, flagp);
}

// Round 3
// 826.163 us; speedup vs baseline: 1.3823x; 1.3823x over previous
//
#include <hip/hip_runtime.h>

// SAERTextRNN on MI355X (gfx950).
// Dims: S=32, B=32, V=32000, H=512, DIN=512, F=50, NL=2.
// R2 -> R3 change: k_gru restructured. 32 WGs x 384 thr (16 per layer, 32 units
// each), weights register-resident (new k_pack layout), cross-WG h exchange via
// relaxed agent-scope 8B atomics (memory-side), one acquire per step, relaxed
// polling (no per-iteration L2 inv), layers software-pipelined. k_grab merged
// into k_rowsum.

typedef unsigned short u16;
typedef unsigned long long ull;
typedef short s16x8 __attribute__((ext_vector_type(8)));
typedef float f32x4 __attribute__((ext_vector_type(4)));

__device__ __forceinline__ float b2f(u16 u) {
    unsigned int x = ((unsigned int)u) << 16; float f; __builtin_memcpy(&f, &x, 4); return f;
}
__device__ __forceinline__ u16 f2b(float f) {
    unsigned int u; __builtin_memcpy(&u, &f, 4);
    unsigned int r = (u + 0x7fffu + ((u >> 16) & 1u)) >> 16; return (u16)r;
}
__device__ __forceinline__ float sigf(float x) { return 1.0f / (1.0f + expf(-x)); }
__device__ __forceinline__ f32x4 mfma(s16x8 a, s16x8 b, f32x4 c) {
    return __builtin_amdgcn_mfma_f32_16x16x32_bf16(a, b, c, 0, 0, 0);
}
// dual-mode 8-element fragment load (elem_off in elements)
__device__ __forceinline__ s16x8 ld8_dual(const void* base, size_t elem_off, bool isf) {
    s16x8 r;
    if (!isf) {
        r = *(const s16x8*)((const u16*)base + elem_off);
    } else {
        const float* f = (const float*)base + elem_off;
        float4 a = *(const float4*)f, b = *(const float4*)(f + 4);
        r[0] = (short)f2b(a.x); r[1] = (short)f2b(a.y); r[2] = (short)f2b(a.z); r[3] = (short)f2b(a.w);
        r[4] = (short)f2b(b.x); r[5] = (short)f2b(b.y); r[6] = (short)f2b(b.z); r[7] = (short)f2b(b.w);
    }
    return r;
}
__device__ __forceinline__ float ld_out1(const void* o, size_t i, bool isf) {
    return isf ? ((const float*)o)[i] : b2f(((const u16*)o)[i]);
}
__device__ __forceinline__ void st_out1(void* o, size_t i, float v, bool isf) {
    if (isf) ((float*)o)[i] = v; else ((u16*)o)[i] = f2b(v);
}
// swizzled LDS fragment read: Bb holds 32 rows x 64 chunks of 16B, chunk c at (c ^ (n&7))
__device__ __forceinline__ s16x8 ldsfrag(const u16* Bb, int n, int kc) {
    return *(const s16x8*)(Bb + ((n * 64 + (kc ^ (n & 7))) << 3));
}

// ---- dtype detect ----
__global__ __launch_bounds__(256) void k_detect(const u16* __restrict__ we, int* flagp) {
    __shared__ int cnt[256];
    int tid = threadIdx.x, c = 0;
    for (int i = 0; i < 16; ++i) {
        u16 u = we[(tid * 16 + i) * 2];
        int e = (u >> 7) & 0xFF;
        c += (e >= 0x68 && e <= 0x7F) ? 1 : 0;
    }
    cnt[tid] = c; __syncthreads();
    for (int s = 128; s > 0; s >>= 1) { if (tid < s) cnt[tid] += cnt[tid + s]; __syncthreads(); }
    if (tid == 0) *flagp = (cnt[0] < 2048) ? 1 : 0;  // 1 = fp32, 0 = bf16
}

// ---- canonicalize 24 small/medium tensors to bf16 ----
struct CArgs { const void* src[24]; int off[25]; int real[24]; };
__global__ __launch_bounds__(256) void k_convert(CArgs a, u16* __restrict__ canon, const int* flagp) {
    int t = blockIdx.x * 256 + threadIdx.x;
    if (t >= a.off[24]) return;
    int i = 0;
#pragma unroll
    for (int j = 1; j < 24; ++j) i += (t >= a.off[j]) ? 1 : 0;
    int local = t - a.off[i];
    u16 v = 0;
    if (local < a.real[i]) {
        if (*flagp) v = f2b(((const float*)a.src[i])[local]);
        else v = ((const u16*)a.src[i])[local];
    }
    canon[t] = v;
}

// ---- pack GRU weights into per-wave register-fragment order ----
// p0: 16 WG x 6 tile x 16 k0 x 64 lane chunks (16B). src row = g*512 + w*32 + usub*16 + r16
//     (g = tile>>1, usub = tile&1, r16 = lane&15), col = k0*32 + (lane>>4)*8. W = Whh0.
// p1: 16 WG x 6 tile x 2 mat x 16 k0 x 64 lane. mat0 = Wih1, mat1 = Whh1, same row formula.
__global__ __launch_bounds__(256) void k_pack(const u16* __restrict__ Whh0,
                                              const u16* __restrict__ Wih1,
                                              const u16* __restrict__ Whh1,
                                              u16* __restrict__ p0, u16* __restrict__ p1) {
    int cid = blockIdx.x * 256 + threadIdx.x;
    if (cid < 98304) {
        int lane = cid & 63, rest = cid >> 6;
        int k0 = rest & 15, jw = rest >> 4;
        int j = jw % 6, w = jw / 6;
        int g = j >> 1, usub = j & 1;
        int r16 = lane & 15, q = lane >> 4;
        int srow = g * 512 + w * 32 + usub * 16 + r16;
        *(s16x8*)(p0 + (size_t)cid * 8) = *(const s16x8*)(Whh0 + (size_t)srow * 512 + k0 * 32 + q * 8);
    } else if (cid < 98304 + 196608) {
        int c2 = cid - 98304;
        int lane = c2 & 63, rest = c2 >> 6;
        int k0 = rest & 15, r2 = rest >> 4;
        int m = r2 & 1, r3 = r2 >> 1;
        int j = r3 % 6, w = r3 / 6;
        int g = j >> 1, usub = j & 1;
        int r16 = lane & 15, q = lane >> 4;
        int srow = g * 512 + w * 32 + usub * 16 + r16;
        const u16* W = m ? Whh1 : Wih1;
        *(s16x8*)(p1 + (size_t)c2 * 8) = *(const s16x8*)(W + (size_t)srow * 512 + k0 * 32 + q * 8);
    }
}

// ---- wave-per-16x16-tile GEMM (unchanged from R2) ----
__global__ __launch_bounds__(256) void k_gemm(const void* __restrict__ A, int amode,
                                              const int* __restrict__ gidx,
                                              const u16* __restrict__ B, const u16* __restrict__ bias,
                                              float* outF, u16* outH, int M, int N, int K, int mode,
                                              const float* __restrict__ rgv, const float* __restrict__ so,
                                              const int* __restrict__ flagp) {
    int wid = blockIdx.x * 4 + (threadIdx.x >> 6);
    int Nt = N >> 4;
    if (wid >= (M >> 4) * Nt) return;
    bool isf = amode && (*flagp != 0);
    int mt = wid / Nt, nt = wid - mt * Nt;
    int lane = threadIdx.x & 63, L15 = lane & 15, q = lane >> 4;
    int am = mt * 16 + L15;
    size_t arow = gidx ? (size_t)gidx[am] : (size_t)am;
    size_t abase = arow * (size_t)K + q * 8;
    const u16* bp = B + (size_t)(nt * 16 + L15) * K + q * 8;
    f32x4 acc = {0.f, 0.f, 0.f, 0.f};
    for (int k0 = 0; k0 < (K >> 5); ++k0) {
        s16x8 a = ld8_dual(A, abase + k0 * 32, isf);
        s16x8 b = *(const s16x8*)(bp + k0 * 32);
        acc = mfma(a, b, acc);
    }
    int n = nt * 16 + L15;
    float bb = b2f(bias[n]);
#pragma unroll
    for (int i = 0; i < 4; ++i) {
        int m = mt * 16 + q * 4 + i;
        float v = acc[i] + bb;
        if (mode == 0) {
            outF[(size_t)m * N + n] = v;
        } else {
            v += rgv[m] * so[(size_t)(m & 31) * 512 + n];
            outH[(size_t)m * N + n] = f2b(tanhf(v));
        }
    }
}

// ---- persistent GRU v2: 32 WGs x 384 thr. bx<16: layer0 (32 units); bx>=16: layer1 ----
__global__ __launch_bounds__(384, 1) void k_gru(const u16* __restrict__ p0, const u16* __restrict__ p1,
                                                const float* __restrict__ gi0,
                                                const u16* __restrict__ bhh0, const u16* __restrict__ bih1,
                                                const u16* __restrict__ bhh1, const u16* __restrict__ inith,
                                                u16* __restrict__ y0, u16* __restrict__ y1,
                                                int* cnt0, int* cnt1) {
    __shared__ __align__(16) unsigned char smem[65536];
    u16* B1 = (u16*)smem;            // 32KB: staged h (32 x 512 bf16, 16B-chunk XOR swizzle)
    u16* B2 = (u16*)(smem + 32768);  // 32KB
    int tid = threadIdx.x;
    int lane = tid & 63, wave = tid >> 6, L15 = lane & 15, q = lane >> 4;
    int bx = blockIdx.x;
    int n0 = L15, n1 = 16 + L15;

    if (bx < 16) {  // ================= layer 0 =================
        int w = bx;
        float* scr = (float*)B2;  // 96 x 33 fp32
        // prologue: register-resident A fragments (64 VGPRs)
        s16x8 areg[16];
#pragma unroll
        for (int k0 = 0; k0 < 16; ++k0)
            areg[k0] = *(const s16x8*)(p0 + (size_t)(((w * 6 + wave) * 16 + k0) * 64 + lane) * 8);

        for (int t = 0; t < 32; ++t) {
            // wait for all layer0 peers to have posted step t-1
            if (t > 0) {
                if (tid == 0) {
                    int it = 0;
                    while (__hip_atomic_load(cnt0 + (t - 1), __ATOMIC_RELAXED, __HIP_MEMORY_SCOPE_AGENT) < 16) {
                        __builtin_amdgcn_s_sleep(1);
                        if (++it > (1 << 20)) break;
                    }
                    __hip_atomic_load(cnt0 + (t - 1), __ATOMIC_ACQUIRE, __HIP_MEMORY_SCOPE_AGENT);
                }
                __syncthreads();
            }
            // stage h_prev -> B1
            for (int cl = tid; cl < 2048; cl += 384) {
                int n = cl >> 6, c = cl & 63;
                ull lo, hi;
                if (t == 0) {
                    const ull* s8 = (const ull*)(inith + n * 512 + c * 8);
                    lo = s8[0]; hi = s8[1];
                } else {
                    const ull* s8 = (const ull*)y0 + ((size_t)(t - 1) * 32 + n) * 128 + c * 2;
                    lo = __hip_atomic_load(s8, __ATOMIC_RELAXED, __HIP_MEMORY_SCOPE_AGENT);
                    hi = __hip_atomic_load(s8 + 1, __ATOMIC_RELAXED, __HIP_MEMORY_SCOPE_AGENT);
                }
                ull* d = (ull*)(B1 + ((n * 64 + (c ^ (n & 7))) << 3));
                d[0] = lo; d[1] = hi;
            }
            __syncthreads();
            // MFMA: wave owns row-tile `wave` (16 rows), both batch halves
            f32x4 acc0 = {0.f, 0.f, 0.f, 0.f}, acc1 = {0.f, 0.f, 0.f, 0.f};
#pragma unroll
            for (int k0 = 0; k0 < 16; ++k0) {
                int kc = (k0 << 2) + q;
                s16x8 b0 = ldsfrag(B1, n0, kc);
                s16x8 b1 = ldsfrag(B1, n1, kc);
                acc0 = mfma(areg[k0], b0, acc0);
                acc1 = mfma(areg[k0], b1, acc1);
            }
#pragma unroll
            for (int i = 0; i < 4; ++i) {
                int rr = wave * 16 + q * 4 + i;
                scr[rr * 33 + n0] = acc0[i];
                scr[rr * 33 + n1] = acc1[i];
            }
            __syncthreads();
            // epilogue: 8 unit-groups x 32 batch = 256 workers
            if (tid < 256) {
                int ug = tid & 7, b = tid >> 3;
                int ul = ug * 4, gu = w * 32 + ul;
                const float* gb = gi0 + ((size_t)t * 32 + b) * 1536 + gu;
                float4 gr = *(const float4*)gb;
                float4 gz = *(const float4*)(gb + 512);
                float4 gn = *(const float4*)(gb + 1024);
                float grA[4] = {gr.x, gr.y, gr.z, gr.w};
                float gzA[4] = {gz.x, gz.y, gz.z, gz.w};
                float gnA[4] = {gn.x, gn.y, gn.z, gn.w};
                ull pack = 0;
#pragma unroll
                for (int i = 0; i < 4; ++i) {
                    int u = ul + i, guu = gu + i;
                    int rr = u >> 4, r16 = u & 15;
                    float hr = scr[((0 + rr) * 16 + r16) * 33 + b] + b2f(bhh0[guu]);
                    float hz = scr[((2 + rr) * 16 + r16) * 33 + b] + b2f(bhh0[512 + guu]);
                    float hn = scr[((4 + rr) * 16 + r16) * 33 + b] + b2f(bhh0[1024 + guu]);
                    float r = sigf(grA[i] + hr), z = sigf(gzA[i] + hz);
                    float nn = tanhf(gnA[i] + r * hn);
                    float hp = b2f(B1[((b * 64 + ((guu >> 3) ^ (b & 7))) << 3) + (guu & 7)]);
                    float h2 = (1.0f - z) * nn + z * hp;
                    pack |= (ull)f2b(h2) << (16 * i);
                }
                __hip_atomic_store((ull*)y0 + (((size_t)t * 32 + b) * 512 + gu) / 4, pack,
                                   __ATOMIC_RELAXED, __HIP_MEMORY_SCOPE_AGENT);
            }
            __syncthreads();  // drains vmcnt -> all stores complete
            if (tid == 0)
                __hip_atomic_fetch_add(cnt0 + t, 1, __ATOMIC_RELEASE, __HIP_MEMORY_SCOPE_AGENT);
        }
    } else {  // ================= layer 1 =================
        int w = bx - 16;
        // prologue: 2 matrices x 16 frags (128 VGPRs)
        s16x8 areg0[16], areg1[16];
#pragma unroll
        for (int k0 = 0; k0 < 16; ++k0) {
            areg0[k0] = *(const s16x8*)(p1 + (size_t)((((w * 6 + wave) * 2 + 0) * 16 + k0) * 64 + lane) * 8);
            areg1[k0] = *(const s16x8*)(p1 + (size_t)((((w * 6 + wave) * 2 + 1) * 16 + k0) * 64 + lane) * 8);
        }
        for (int t = 0; t < 32; ++t) {
            if (tid == 0) {
                int it = 0;
                while (__hip_atomic_load(cnt0 + t, __ATOMIC_RELAXED, __HIP_MEMORY_SCOPE_AGENT) < 16) {
                    __builtin_amdgcn_s_sleep(1);
                    if (++it > (1 << 20)) break;
                }
                if (t > 0) {
                    it = 0;
                    while (__hip_atomic_load(cnt1 + (t - 1), __ATOMIC_RELAXED, __HIP_MEMORY_SCOPE_AGENT) < 16) {
                        __builtin_amdgcn_s_sleep(1);
                        if (++it > (1 << 20)) break;
                    }
                }
                __hip_atomic_load(cnt0 + t, __ATOMIC_ACQUIRE, __HIP_MEMORY_SCOPE_AGENT);
            }
            __syncthreads();
            // stage y0[t] -> B1 (atomic), h1_prev -> B2
            for (int cl = tid; cl < 2048; cl += 384) {
                int n = cl >> 6, c = cl & 63;
                const ull* sa = (const ull*)y0 + ((size_t)t * 32 + n) * 128 + c * 2;
                ull lo = __hip_atomic_load(sa, __ATOMIC_RELAXED, __HIP_MEMORY_SCOPE_AGENT);
                ull hi = __hip_atomic_load(sa + 1, __ATOMIC_RELAXED, __HIP_MEMORY_SCOPE_AGENT);
                ull* d = (ull*)(B1 + ((n * 64 + (c ^ (n & 7))) << 3));
                d[0] = lo; d[1] = hi;
                ull lo2, hi2;
                if (t == 0) {
                    const ull* s8 = (const ull*)(inith + 16384 + n * 512 + c * 8);
                    lo2 = s8[0]; hi2 = s8[1];
                } else {
                    const ull* sb = (const ull*)y1 + ((size_t)(t - 1) * 32 + n) * 128 + c * 2;
                    lo2 = __hip_atomic_load(sb, __ATOMIC_RELAXED, __HIP_MEMORY_SCOPE_AGENT);
                    hi2 = __hip_atomic_load(sb + 1, __ATOMIC_RELAXED, __HIP_MEMORY_SCOPE_AGENT);
                }
                ull* d2 = (ull*)(B2 + ((n * 64 + (c ^ (n & 7))) << 3));
                d2[0] = lo2; d2[1] = hi2;
            }
            __syncthreads();
            f32x4 a00 = {0.f,0.f,0.f,0.f}, a01 = {0.f,0.f,0.f,0.f};
            f32x4 a10 = {0.f,0.f,0.f,0.f}, a11 = {0.f,0.f,0.f,0.f};
#pragma unroll
            for (int k0 = 0; k0 < 16; ++k0) {
                int kc = (k0 << 2) + q;
                s16x8 b0 = ldsfrag(B1, n0, kc);
                s16x8 b1 = ldsfrag(B1, n1, kc);
                s16x8 c0 = ldsfrag(B2, n0, kc);
                s16x8 c1 = ldsfrag(B2, n1, kc);
                a00 = mfma(areg0[k0], b0, a00);
                a01 = mfma(areg0[k0], b1, a01);
                a10 = mfma(areg1[k0], c0, a10);
                a11 = mfma(areg1[k0], c1, a11);
            }
            __syncthreads();  // done reading B1; scr aliases it
            float* scr = (float*)B1;  // 192 x 33 fp32 (25.3KB)
#pragma unroll
            for (int i = 0; i < 4; ++i) {
                int rr = wave * 16 + q * 4 + i;
                scr[rr * 33 + n0] = a00[i];
                scr[rr * 33 + n1] = a01[i];
                scr[(96 + rr) * 33 + n0] = a10[i];
                scr[(96 + rr) * 33 + n1] = a11[i];
            }
            __syncthreads();
            if (tid < 256) {
                int ug = tid & 7, b = tid >> 3;
                int ul = ug * 4, gu = w * 32 + ul;
                ull pack = 0;
#pragma unroll
                for (int i = 0; i < 4; ++i) {
                    int u = ul + i, guu = gu + i;
                    int rr = u >> 4, r16 = u & 15;
                    int r0 = ((0 + rr) * 16 + r16) * 33 + b;
                    int r1 = ((2 + rr) * 16 + r16) * 33 + b;
                    int r2 = ((4 + rr) * 16 + r16) * 33 + b;
                    float ir = scr[r0] + b2f(bih1[guu]);
                    float iz = scr[r1] + b2f(bih1[512 + guu]);
                    float inn = scr[r2] + b2f(bih1[1024 + guu]);
                    float hr = scr[96 * 33 + r0] + b2f(bhh1[guu]);
                    float hz = scr[96 * 33 + r1] + b2f(bhh1[512 + guu]);
                    float hn = scr[96 * 33 + r2] + b2f(bhh1[1024 + guu]);
                    float r = sigf(ir + hr), z = sigf(iz + hz);
                    float nn = tanhf(inn + r * hn);
                    float hp = b2f(B2[((b * 64 + ((guu >> 3) ^ (b & 7))) << 3) + (guu & 7)]);
                    float h2 = (1.0f - z) * nn + z * hp;
                    pack |= (ull)f2b(h2) << (16 * i);
                }
                __hip_atomic_store((ull*)y1 + (((size_t)t * 32 + b) * 512 + gu) / 4, pack,
                                   __ATOMIC_RELAXED, __HIP_MEMORY_SCOPE_AGENT);
            }
            __syncthreads();
            if (tid == 0)
                __hip_atomic_fetch_add(cnt1 + t, 1, __ATOMIC_RELEASE, __HIP_MEMORY_SCOPE_AGENT);
        }
    }
}

// ---- fs(16), fg, rg per (s,b) row ----
__global__ __launch_bounds__(64) void k_fsfgrg(const u16* __restrict__ y1,
                                               const u16* __restrict__ Wfs, const u16* __restrict__ bfs,
                                               const u16* __restrict__ Wfg, const u16* __restrict__ bfg,
                                               const u16* __restrict__ Wrg, const u16* __restrict__ brg,
                                               float* fsv, float* fgv, float* rgv) {
    int m = blockIdx.x, lane = threadIdx.x;
    s16x8 av = *(const s16x8*)(y1 + (size_t)m * 512 + lane * 8);
    float af[8];
#pragma unroll
    for (int e = 0; e < 8; ++e) af[e] = b2f((u16)av[e]);
    for (int j = 0; j < 18; ++j) {
        const u16* w = (j < 16) ? (Wfs + (size_t)j * 512) : ((j == 16) ? Wfg : Wrg);
        s16x8 wv = *(const s16x8*)(w + lane * 8);
        float p = 0.f;
#pragma unroll
        for (int e = 0; e < 8; ++e) p += af[e] * b2f((u16)wv[e]);
        for (int off = 32; off > 0; off >>= 1) p += __shfl_xor(p, off);
        if (lane == 0) {
            if (j < 16) fsv[(size_t)m * 16 + j] = p + b2f(bfs[j]);
            else if (j == 16) fgv[m] = sigf(p + b2f(bfg[0]));
            else rgv[m] = sigf(p + b2f(brg[0]));
        }
    }
}

// ---- attention softmax over F=50 ----
__global__ __launch_bounds__(64) void k_attn(const float* __restrict__ fsv,
                                             const u16* __restrict__ user, const u16* __restrict__ item,
                                             const float* __restrict__ energy, float* __restrict__ fattn) {
    int m = blockIdx.x, b = m & 31, f = threadIdx.x;
    __shared__ float qv[80];
    for (int j = f; j < 80; j += 64)
        qv[j] = (j < 16) ? fsv[(size_t)m * 16 + j]
                         : ((j < 48) ? b2f(user[b * 32 + (j - 16)]) : b2f(item[b * 32 + (j - 48)]));
    __syncthreads();
    float sc = -1e30f;
    if (f < 50) {
        const float* ep = energy + ((size_t)b * 50 + f) * 80;
        float s = 0.f;
        for (int e = 0; e < 80; ++e) s += qv[e] * ep[e];
        sc = s;
    }
    float mx = sc;
    for (int off = 32; off > 0; off >>= 1) mx = fmaxf(mx, __shfl_xor(mx, off));
    float ev = (f < 50) ? expf(sc - mx) : 0.f;
    float sm = ev;
    for (int off = 32; off > 0; off >>= 1) sm += __shfl_xor(sm, off);
    if (f < 50) fattn[(size_t)m * 50 + f] = ev / sm;
}

// ---- score_out = ui_var @ Wso^T + bso ----
__global__ __launch_bounds__(256) void k_scoreout(const u16* __restrict__ ui, const u16* __restrict__ Wso,
                                                  const u16* __restrict__ bso, float* so) {
    int b = blockIdx.x, tid = threadIdx.x;
    __shared__ float uiL[32];
    if (tid < 32) uiL[tid] = b2f(ui[b * 32 + tid]);
    __syncthreads();
    for (int n = tid; n < 512; n += 256) {
        float s = b2f(bso[n]);
        const u16* w = Wso + (size_t)n * 32;
        for (int k = 0; k < 32; ++k) s += uiL[k] * b2f(w[k]);
        so[(size_t)b * 512 + n] = s;
    }
}

// ---- big GEMM: out = ho @ Wout^T + bout ----
__global__ __launch_bounds__(256) void k_big(const u16* __restrict__ A, const void* __restrict__ W,
                                             const void* __restrict__ boutp, void* __restrict__ out,
                                             const int* __restrict__ flagp) {
    __shared__ __align__(16) u16 lA[8192], lB[8192];
    bool isf = (*flagp != 0);
    int tid = threadIdx.x;
    int bm = blockIdx.x & 15, bn = blockIdx.x >> 4;
    int lane = tid & 63, wave = tid >> 6, L15 = lane & 15, q = lane >> 4;
    f32x4 zero = {0.f, 0.f, 0.f, 0.f};
    f32x4 acc[4] = {zero, zero, zero, zero};
    int cs = tid & 15, rs = tid >> 4;
    for (int ko = 0; ko < 4; ++ko) {
        __syncthreads();
        for (int rr = rs; rr < 64; rr += 16) {
            *(s16x8*)(lA + ((rr * 16 + (cs ^ (rr & 7))) << 3)) =
                *(const s16x8*)(A + (size_t)(bm * 64 + rr) * 512 + ko * 128 + cs * 8);
            *(s16x8*)(lB + ((rr * 16 + (cs ^ (rr & 7))) << 3)) =
                ld8_dual(W, (size_t)(bn * 64 + rr) * 512 + ko * 128 + cs * 8, isf);
        }
        __syncthreads();
        int ra = wave * 16 + L15;
#pragma unroll
        for (int k0 = 0; k0 < 4; ++k0) {
            int cc = k0 * 4 + q;
            s16x8 a = *(const s16x8*)(lA + ((ra * 16 + (cc ^ (ra & 7))) << 3));
#pragma unroll
            for (int ct = 0; ct < 4; ++ct) {
                int rb = ct * 16 + L15;
                s16x8 b = *(const s16x8*)(lB + ((rb * 16 + (cc ^ (rb & 7))) << 3));
                acc[ct] = mfma(a, b, acc[ct]);
            }
        }
    }
#pragma unroll
    for (int ct = 0; ct < 4; ++ct) {
        int n = bn * 64 + ct * 16 + L15;
        float bb = isf ? ((const float*)boutp)[n] : b2f(((const u16*)boutp)[n]);
#pragma unroll
        for (int i = 0; i < 4; ++i) {
            int m = bm * 64 + wave * 16 + q * 4 + i;
            st_out1(out, (size_t)m * 32000 + n, acc[ct][i] + bb, isf);
        }
    }
}

// ---- per-row max & exp-sum + grab scattered logits; D = log(1-fg) - log Z - m ----
__global__ __launch_bounds__(256) void k_rowsum(const void* __restrict__ out, const float* __restrict__ fgv,
                                                const int* __restrict__ ifeat, float* __restrict__ tmpl,
                                                float* Dv, float* Zv, float* Mv, const int* __restrict__ flagp) {
    bool isf = (*flagp != 0);
    int row = blockIdx.x, tid = threadIdx.x;
    if (tid < 50) {
        int idx = ifeat[(row & 31) * 50 + tid];
        tmpl[(size_t)row * 50 + tid] = ld_out1(out, (size_t)row * 32000 + idx, isf);
    }
    __shared__ float red[256];
    float mx = -1e30f;
    for (int c = tid; c < 4000; c += 256) {
        float v[8];
        if (isf) {
            const float* p = (const float*)out + (size_t)row * 32000 + c * 8;
            float4 x = *(const float4*)p, y = *(const float4*)(p + 4);
            v[0]=x.x; v[1]=x.y; v[2]=x.z; v[3]=x.w; v[4]=y.x; v[5]=y.y; v[6]=y.z; v[7]=y.w;
        } else {
            s16x8 h = *(const s16x8*)((const u16*)out + (size_t)row * 32000 + c * 8);
#pragma unroll
            for (int e = 0; e < 8; ++e) v[e] = b2f((u16)h[e]);
        }
#pragma unroll
        for (int e = 0; e < 8; ++e) mx = fmaxf(mx, v[e]);
    }
    red[tid] = mx; __syncthreads();
    for (int s = 128; s > 0; s >>= 1) { if (tid < s) red[tid] = fmaxf(red[tid], red[tid + s]); __syncthreads(); }
    mx = red[0]; __syncthreads();
    float sum = 0.f;
    for (int c = tid; c < 4000; c += 256) {
        float v[8];
        if (isf) {
            const float* p = (const float*)out + (size_t)row * 32000 + c * 8;
            float4 x = *(const float4*)p, y = *(const float4*)(p + 4);
            v[0]=x.x; v[1]=x.y; v[2]=x.z; v[3]=x.w; v[4]=y.x; v[5]=y.y; v[6]=y.z; v[7]=y.w;
        } else {
            s16x8 h = *(const s16x8*)((const u16*)out + (size_t)row * 32000 + c * 8);
#pragma unroll
            for (int e = 0; e < 8; ++e) v[e] = b2f((u16)h[e]);
        }
#pragma unroll
        for (int e = 0; e < 8; ++e) sum += expf(v[e] - mx);
    }
    red[tid] = sum; __syncthreads();
    for (int s = 128; s > 0; s >>= 1) { if (tid < s) red[tid] += red[tid + s]; __syncthreads(); }
    if (tid == 0) {
        float Z = red[0], fg = fgv[row];
        Mv[row] = mx; Zv[row] = Z;
        Dv[row] = logf(1.0f - fg) - logf(Z) - mx;
    }
}

// ---- in-place: out = l + D[row] ----
__global__ __launch_bounds__(256) void k_final(void* __restrict__ out, const float* __restrict__ Dv,
                                               const int* __restrict__ flagp) {
    bool isf = (*flagp != 0);
    int row = blockIdx.y;
    int c = blockIdx.x * 256 + threadIdx.x;
    if (c >= 4000) return;
    float D = Dv[row];
    size_t base = (size_t)row * 32000 + (size_t)c * 8;
    if (isf) {
        float* p = (float*)out + base;
        float4 x = *(const float4*)p, y = *(const float4*)(p + 4);
        x.x += D; x.y += D; x.z += D; x.w += D;
        y.x += D; y.y += D; y.z += D; y.w += D;
        *(float4*)p = x; *(float4*)(p + 4) = y;
    } else {
        u16* p = (u16*)out + base;
        s16x8 v = *(const s16x8*)p, r;
#pragma unroll
        for (int e = 0; e < 8; ++e) r[e] = (short)f2b(b2f((u16)v[e]) + D);
        *(s16x8*)p = r;
    }
}

// ---- exact fix-up at scattered entries ----
__global__ __launch_bounds__(256) void k_fixup(const float* __restrict__ tmpl, const int* __restrict__ ifeat,
                                               const float* __restrict__ Mv, const float* __restrict__ Zv,
                                               const float* __restrict__ fgv, const float* __restrict__ fattn,
                                               void* __restrict__ out, const int* __restrict__ flagp) {
    bool isf = (*flagp != 0);
    int id = blockIdx.x * 256 + threadIdx.x;
    if (id >= 51200) return;
    int m = id / 50, f = id - m * 50, b = m & 31;
    int idx = ifeat[b * 50 + f];
    float p = expf(tmpl[id] - Mv[m]) / Zv[m];
    float fg = fgv[m];
    float val = (1.0f - fg) * p + fg * fattn[(size_t)m * 50 + f];
    st_out1(out, (size_t)m * 32000 + idx, logf(val), isf);
}

extern "C" void kernel_launch(void* const* d_in, const int* in_sizes, int n_in,
                              void* d_out, int out_size, void* d_ws, size_t ws_size,
                              hipStream_t stream) {
    const int* input_seq = (const int*)d_in[0];
    const int* i_features = (const int*)d_in[5];
    const void* word_ebd = d_in[7];
    const void* Wout = d_in[16];
    const void* bout = d_in[17];
    char* ob = (char*)d_out;
    char* w = (char*)d_ws;

    // ws layout (~1.61 MB)
    int* cnt0 = (int*)(w + 0);
    int* cnt1 = (int*)(w + 128);
    int* flagp = (int*)(w + 256);
    float* Dv = (float*)(w + 512);
    float* Zv = (float*)(w + 4608);
    float* Mv = (float*)(w + 8704);
    float* fgv = (float*)(w + 12800);
    float* rgv = (float*)(w + 16896);
    float* fsv = (float*)(w + 20992);    // 64 KB
    float* so = (float*)(w + 86528);     // 64 KB
    float* fattn = (float*)(w + 152064); // 200 KB
    float* tmpl = (float*)(w + 356864);  // 200 KB
    u16* ho = (u16*)(w + 561664);        // 1 MB

    // d_out scratch (consumed before k_big rewrites d_out)
    u16* canon = (u16*)(ob + 0);
    u16* p0 = (u16*)(ob + 7035136);          // 1.5 MB
    u16* p1 = (u16*)(ob + 8608000);          // 3 MB used (4 MB slot)
    float* gi0 = (float*)(ob + 12802304);    // 6 MB
    float* energy = (float*)(ob + 19093760); // 0.5 MB
    u16* y0 = (u16*)(ob + 19605760);         // 1 MB
    u16* y1 = (u16*)(ob + 20654336);         // 1 MB

    static const int din_idx[24] = {1,2,3,4, 8,9,10,11, 12,13,14,15, 18,19,20,21, 22,23,24,25, 26,27,28,29};
    static const int padsz[24] = {32768,1024,1024,1024, 786432,786432,1536,1536, 786432,786432,1536,1536,
                                  512,8,16384,512, 262144,512,512,8, 8192,16,40960,80};
    CArgs ca;
    int off = 0;
    for (int i = 0; i < 24; ++i) {
        ca.src[i] = d_in[din_idx[i]];
        ca.off[i] = off;
        ca.real[i] = padsz[i];
        off += padsz[i];
    }
    ca.real[13] = 1; ca.real[19] = 1;  // brg, bfg scalars
    ca.off[24] = off;
    const u16 *c_inith = canon + ca.off[0], *c_user = canon + ca.off[1], *c_item = canon + ca.off[2],
              *c_uivar = canon + ca.off[3], *c_Wih0 = canon + ca.off[4], *c_Whh0 = canon + ca.off[5],
              *c_bih0 = canon + ca.off[6], *c_bhh0 = canon + ca.off[7], *c_Wih1 = canon + ca.off[8],
              *c_Whh1 = canon + ca.off[9], *c_bih1 = canon + ca.off[10], *c_bhh1 = canon + ca.off[11],
              *c_Wrg = canon + ca.off[12], *c_brg = canon + ca.off[13], *c_Wso = canon + ca.off[14],
              *c_bso = canon + ca.off[15], *c_Woo = canon + ca.off[16], *c_boo = canon + ca.off[17],
              *c_Wfg = canon + ca.off[18], *c_bfg = canon + ca.off[19], *c_Wfs = canon + ca.off[20],
              *c_bfs = canon + ca.off[21], *c_Wfa = canon + ca.off[22], *c_bfa = canon + ca.off[23];

    hipMemsetAsync(d_ws, 0, 512, stream);
    k_detect<<<1, 256, 0, stream>>>((const u16*)word_ebd, flagp);
    k_convert<<<(off + 255) / 256, 256, 0, stream>>>(ca, canon, flagp);
    k_pack<<<1152, 256, 0, stream>>>(c_Whh0, c_Wih1, c_Whh1, p0, p1);
    k_gemm<<<1536, 256, 0, stream>>>(word_ebd, 1, input_seq, c_Wih0, c_bih0, gi0, nullptr,
                                     1024, 1536, 512, 0, nullptr, nullptr, flagp);
    k_gemm<<<125, 256, 0, stream>>>(word_ebd, 1, i_features, c_Wfa, c_bfa, energy, nullptr,
                                    1600, 80, 512, 0, nullptr, nullptr, flagp);
    k_scoreout<<<32, 256, 0, stream>>>(c_uivar, c_Wso, c_bso, so);
    k_gru<<<32, 384, 0, stream>>>(p0, p1, gi0, c_bhh0, c_bih1, c_bhh1, c_inith, y0, y1, cnt0, cnt1);
    k_fsfgrg<<<1024, 64, 0, stream>>>(y1, c_Wfs, c_bfs, c_Wfg, c_bfg, c_Wrg, c_brg, fsv, fgv, rgv);
    k_attn<<<1024, 64, 0, stream>>>(fsv, c_user, c_item, energy, fattn);
    k_gemm<<<512, 256, 0, stream>>>(y1, 0, nullptr, c_Woo, c_boo, nullptr, ho,
                                    1024, 512, 512, 1, rgv, so, flagp);
    k_big<<<8000, 256, 0, stream>>>(ho, Wout, bout, d_out, flagp);
    k_rowsum<<<1024, 256, 0, stream>>>(d_out, fgv, i_features, tmpl, Dv, Zv, Mv, flagp);
    k_final<<<dim3(16, 1024), 256, 0, stream>>>(d_out, Dv, flagp);
    k_fixup<<<200, 256, 0, stream>>>(tmpl, i_features, Mv, Zv, fgv, fattn, d_out, flagp);
}